// Round 4
// baseline (1925.288 us; speedup 1.0000x reference)
//
#include <hip/hip_runtime.h>
#include <cfloat>
#include <cmath>

#define NB 128
#define NL 48
#define HID 512
#define NSLOT 48
#define NN 2560              // 5*HID output cols
#define NNODE (NB*NSLOT)     // 6144
#define AROWS (NB*(NL-1))    // 6016 phase-A pair rows
#define SROWS (NB*2)         // 256 per-step refresh pairs

// ---------------- workspace layout (float units) ----------------
static const size_t offH    = 0;                                   // [B][48][512]
static const size_t offC    = offH  + (size_t)NNODE*HID;
static const size_t offCH   = offC  + (size_t)NNODE*HID;           // candidate h
static const size_t offCC   = offCH + (size_t)NNODE*HID;           // candidate c
static const size_t offLG   = offCC + (size_t)NNODE*HID;           // logits [B][48]
static const size_t offNXT  = offLG  + NNODE;                      // int
static const size_t offPRV  = offNXT + NNODE;                      // int
static const size_t offROWS = offPRV + NNODE;                      // int4 x 256
static const size_t offROWSA= offROWS + (size_t)4*SROWS;           // int4 x 6016
static const size_t offROWSN= offROWSA + (size_t)4*AROWS;          // int x 6144
static const size_t offPROW = offROWSN + NNODE;                    // int x 128
static const size_t offBIG  = offPROW + 128;
// then: [V partials (KS=2): 2*2*NB*NN floats, if ws allows] PL, PR (NNODE*NN each)

__device__ __forceinline__ float sigf(float x){ return 1.0f/(1.0f+expf(-x)); }

// ---------------- init: copy input -> H,C ; init links/logits ----------------
__global__ void k_init(const float* __restrict__ in, const int* __restrict__ len,
                       float* __restrict__ H, float* __restrict__ Cc,
                       float* __restrict__ LG, int* __restrict__ NXT,
                       int* __restrict__ PRV, int4* __restrict__ ROWS)
{
    int bs = blockIdx.x;            // b*48+s
    int b  = bs / NSLOT, s = bs % NSLOT;
    int t  = threadIdx.x;           // 256 threads, 1 float4 each
    const float4* inrow = (const float4*)(in + (size_t)bs*2*HID);
    float4 v = inrow[t];
    if (t < 128) ((float4*)(H  + (size_t)bs*HID))[t]       = v;
    else         ((float4*)(Cc + (size_t)bs*HID))[t - 128] = v;
    if (t == 0) {
        int lb = len[b];
        NXT[bs] = (s+1 < lb) ? s+1 : -1;
        PRV[bs] = (s > 0 && s < lb) ? s-1 : -1;
        LG[bs]  = -FLT_MAX;
        if (s == 0) {
            ROWS[b*2+0] = make_int4(0,0,0,-1);
            ROWS[b*2+1] = make_int4(0,0,0,-1);
        }
    }
}

// ---------------- descriptors: pair rows (phase A) + node rows ----------------
__global__ void k_descA(const int* __restrict__ len, int4* __restrict__ ROWSA,
                        int* __restrict__ ROWSN)
{
    int r = blockIdx.x*256 + threadIdx.x;
    if (r < NNODE) ROWSN[r] = r;
    if (r >= AROWS) return;
    int b = r/(NL-1), s = r%(NL-1);
    int lb = len[b];
    ROWSA[r] = make_int4(b, s, s+1, (s <= lb-2) ? s : -1);
}

// ================= split-W product GEMM (direct write to PL/PR) =================
// PL[node][n] = sum_k H[node][k]*W[n][k],  PR[node][n] = sum_k H[node][k]*W[n][512+k]
// Virtual N=5120: vn<2560 -> PL, else PR. BN=64 (block entirely one side).
template<int MI, int KT>
__global__ __launch_bounds__(256, 6)
void k_gemmP(const int* __restrict__ rows,
             const float* __restrict__ H, const float* __restrict__ W,
             float* __restrict__ PL, float* __restrict__ PR)
{
    constexpr int BM  = 16*MI;
    constexpr int AF4 = BM/64;
    constexpr int LDA = BM + 4;
    constexpr int LDB = 68;
    __shared__ float As[2][16*LDA];
    __shared__ float Bs[2][16*LDB];

    const int t   = threadIdx.x;
    const int m0  = blockIdx.x*BM;
    const int vn0 = blockIdx.y*64;
    const int side = (vn0 >= NN);
    const int n0  = side ? vn0 - NN : vn0;
    float* OUT = side ? PR : PL;

    int aoff[AF4], arow[AF4], aseg[AF4];
    #pragma unroll
    for (int j=0;j<AF4;++j){
        int f = t*AF4 + j;
        arow[j] = f >> 2; aseg[j] = f & 3;
        aoff[j] = rows[m0 + arow[j]]*HID + aseg[j]*4;
    }
    const int brow = t >> 2, bseg = t & 3;
    const float* wptr = W + (size_t)(n0 + brow)*1024 + side*HID + bseg*4;

    const int tm = t >> 4, tn = t & 15;

    float acc[MI][4];
    #pragma unroll
    for (int mi=0;mi<MI;++mi)
        #pragma unroll
        for (int j=0;j<4;++j) acc[mi][j]=0.f;

    float4 av[AF4], bv;
    auto gload = [&](int kt){
        int kg = kt*16;
        #pragma unroll
        for (int j=0;j<AF4;++j) av[j] = *(const float4*)(H + aoff[j] + kg);
        bv = *(const float4*)(wptr + kg);
    };
    auto swrite = [&](int buf){
        #pragma unroll
        for (int j=0;j<AF4;++j){
            As[buf][(aseg[j]*4+0)*LDA + arow[j]] = av[j].x;
            As[buf][(aseg[j]*4+1)*LDA + arow[j]] = av[j].y;
            As[buf][(aseg[j]*4+2)*LDA + arow[j]] = av[j].z;
            As[buf][(aseg[j]*4+3)*LDA + arow[j]] = av[j].w;
        }
        Bs[buf][(bseg*4+0)*LDB + brow] = bv.x;
        Bs[buf][(bseg*4+1)*LDB + brow] = bv.y;
        Bs[buf][(bseg*4+2)*LDB + brow] = bv.z;
        Bs[buf][(bseg*4+3)*LDB + brow] = bv.w;
    };

    gload(0); swrite(0); __syncthreads();

    for (int kt=0; kt<KT; ++kt){
        int buf = kt & 1;
        if (kt+1 < KT) gload(kt+1);
        #pragma unroll
        for (int k=0;k<16;++k){
            float a[MI];
            #pragma unroll
            for (int mi=0;mi<MI;mi+=4){
                float4 a4 = *(const float4*)&As[buf][k*LDA + tm*MI + mi];
                a[mi]=a4.x; a[mi+1]=a4.y; a[mi+2]=a4.z; a[mi+3]=a4.w;
            }
            float4 b4 = *(const float4*)&Bs[buf][k*LDB + tn*4];
            #pragma unroll
            for (int mi=0;mi<MI;++mi){
                acc[mi][0] = fmaf(a[mi], b4.x, acc[mi][0]);
                acc[mi][1] = fmaf(a[mi], b4.y, acc[mi][1]);
                acc[mi][2] = fmaf(a[mi], b4.z, acc[mi][2]);
                acc[mi][3] = fmaf(a[mi], b4.w, acc[mi][3]);
            }
        }
        if (kt+1 < KT) swrite(buf^1);
        __syncthreads();
    }

    #pragma unroll
    for (int mi=0;mi<MI;++mi){
        int row = m0 + tm*MI + mi;
        float4 o; o.x=acc[mi][0]; o.y=acc[mi][1]; o.z=acc[mi][2]; o.w=acc[mi][3];
        *(float4*)(OUT + (size_t)rows[row]*NN + n0 + tn*4) = o;
    }
}

// ================= K-split refresh GEMM -> V partials =================
// grid (M/64, 160, 2). V[((kz*2+side)*NB + row)*NN + n] = partial over K=256.
template<int MI, int KT>
__global__ __launch_bounds__(256, 4)
void k_gemmPV(const int* __restrict__ rows,
              const float* __restrict__ H, const float* __restrict__ W,
              float* __restrict__ V)
{
    constexpr int BM  = 16*MI;
    constexpr int AF4 = BM/64;
    constexpr int LDA = BM + 4;
    constexpr int LDB = 68;
    __shared__ float As[2][16*LDA];
    __shared__ float Bs[2][16*LDB];

    const int t   = threadIdx.x;
    const int m0  = blockIdx.x*BM;
    const int vn0 = blockIdx.y*64;
    const int side = (vn0 >= NN);
    const int n0  = side ? vn0 - NN : vn0;
    const int kz  = blockIdx.z;
    const int kg0 = kz*KT*16;

    int aoff[AF4], arow[AF4], aseg[AF4];
    #pragma unroll
    for (int j=0;j<AF4;++j){
        int f = t*AF4 + j;
        arow[j] = f >> 2; aseg[j] = f & 3;
        aoff[j] = rows[m0 + arow[j]]*HID + aseg[j]*4 + kg0;
    }
    const int brow = t >> 2, bseg = t & 3;
    const float* wptr = W + (size_t)(n0 + brow)*1024 + side*HID + bseg*4 + kg0;

    const int tm = t >> 4, tn = t & 15;

    float acc[MI][4];
    #pragma unroll
    for (int mi=0;mi<MI;++mi)
        #pragma unroll
        for (int j=0;j<4;++j) acc[mi][j]=0.f;

    float4 av[AF4], bv;
    auto gload = [&](int kt){
        int kg = kt*16;
        #pragma unroll
        for (int j=0;j<AF4;++j) av[j] = *(const float4*)(H + aoff[j] + kg);
        bv = *(const float4*)(wptr + kg);
    };
    auto swrite = [&](int buf){
        #pragma unroll
        for (int j=0;j<AF4;++j){
            As[buf][(aseg[j]*4+0)*LDA + arow[j]] = av[j].x;
            As[buf][(aseg[j]*4+1)*LDA + arow[j]] = av[j].y;
            As[buf][(aseg[j]*4+2)*LDA + arow[j]] = av[j].z;
            As[buf][(aseg[j]*4+3)*LDA + arow[j]] = av[j].w;
        }
        Bs[buf][(bseg*4+0)*LDB + brow] = bv.x;
        Bs[buf][(bseg*4+1)*LDB + brow] = bv.y;
        Bs[buf][(bseg*4+2)*LDB + brow] = bv.z;
        Bs[buf][(bseg*4+3)*LDB + brow] = bv.w;
    };

    gload(0); swrite(0); __syncthreads();

    for (int kt=0; kt<KT; ++kt){
        int buf = kt & 1;
        if (kt+1 < KT) gload(kt+1);
        #pragma unroll
        for (int k=0;k<16;++k){
            float a[MI];
            #pragma unroll
            for (int mi=0;mi<MI;mi+=4){
                float4 a4 = *(const float4*)&As[buf][k*LDA + tm*MI + mi];
                a[mi]=a4.x; a[mi+1]=a4.y; a[mi+2]=a4.z; a[mi+3]=a4.w;
            }
            float4 b4 = *(const float4*)&Bs[buf][k*LDB + tn*4];
            #pragma unroll
            for (int mi=0;mi<MI;++mi){
                acc[mi][0] = fmaf(a[mi], b4.x, acc[mi][0]);
                acc[mi][1] = fmaf(a[mi], b4.y, acc[mi][1]);
                acc[mi][2] = fmaf(a[mi], b4.z, acc[mi][2]);
                acc[mi][3] = fmaf(a[mi], b4.w, acc[mi][3]);
            }
        }
        if (kt+1 < KT) swrite(buf^1);
        __syncthreads();
    }

    #pragma unroll
    for (int mi=0;mi<MI;++mi){
        int row = m0 + tm*MI + mi;      // = batch index (M = NB)
        float4 o; o.x=acc[mi][0]; o.y=acc[mi][1]; o.z=acc[mi][2]; o.w=acc[mi][3];
        *(float4*)(V + ((size_t)(kz*2+side)*NB + row)*NN + n0 + tn*4) = o;
    }
}

// ---------------- phase-A combine: v = PL[l]+PR[r]+bias -> gates -> CH/CC + logit ----------------
__global__ void k_combineP(const int4* __restrict__ rows,
                           const float* __restrict__ PL, const float* __restrict__ PR,
                           const float* __restrict__ Cc, const float* __restrict__ bias,
                           const float* __restrict__ q,
                           float* __restrict__ CH, float* __restrict__ CC,
                           float* __restrict__ LG)
{
    int4 rd = rows[blockIdx.x];
    if (rd.w < 0) return;
    int t = threadIdx.x;
    int b = rd.x, sl = rd.y, sr = rd.z, dst = rd.w;
    const float* pl = PL + (size_t)(b*NSLOT+sl)*NN;
    const float* pr = PR + (size_t)(b*NSLOT+sr)*NN;
    const float* cl = Cc + (size_t)(b*NSLOT+sl)*HID;
    const float* cr = Cc + (size_t)(b*NSLOT+sr)*HID;
    float part = 0.f;
    #pragma unroll
    for (int h2=0; h2<2; ++h2){
        int c = t + h2*256;
        float v[5];
        #pragma unroll
        for (int g=0; g<5; ++g)
            v[g] = pl[g*HID+c] + pr[g*HID+c] + bias[g*HID+c];
        float cn = cl[c]*sigf(v[1]+1.f) + cr[c]*sigf(v[2]+1.f) + tanhf(v[3])*sigf(v[0]);
        float hn = sigf(v[4])*tanhf(cn);
        CH[(size_t)(b*NSLOT+dst)*HID + c] = hn;
        CC[(size_t)(b*NSLOT+dst)*HID + c] = cn;
        part += q[c]*hn;
    }
    __shared__ float red[4];
    #pragma unroll
    for (int off=32; off; off>>=1) part += __shfl_xor(part, off);
    if ((t & 63) == 0) red[t>>6] = part;
    __syncthreads();
    if (t == 0) LG[b*NSLOT + dst] = red[0]+red[1]+red[2]+red[3];
}

// ---------------- fused: finish 2 pairs + PL/PR fixup + argmax + commit + relink ----------------
// one block per batch. FROMV: partials in V (KS splits); else PL/PR already final.
template<bool FROMV>
__global__ __launch_bounds__(256, 4)
void k_combineStep(int i, const int* __restrict__ len, int KS,
                   const float* __restrict__ V,
                   float* __restrict__ PL, float* __restrict__ PR,
                   int4* __restrict__ ROWS, int* __restrict__ PROW,
                   float* __restrict__ H, float* __restrict__ Cc,
                   float* __restrict__ CH, float* __restrict__ CC,
                   float* __restrict__ LG, int* __restrict__ NXT,
                   int* __restrict__ PRV,
                   const float* __restrict__ bias, const float* __restrict__ q)
{
    int b = blockIdx.x, t = threadIdx.x;
    int base = b*NSLOT;
    int4 r0 = ROWS[b*2+0], r1 = ROWS[b*2+1];
    bool v0 = (r0.w >= 0), v1 = (r1.w >= 0);
    int node = PROW[b];                       // node merged at step i-1
    __shared__ float slg[NSLOT];
    __shared__ float red[8];
    __shared__ int ss[1];

    // --- PL/PR of new node: sum partials (or read), keep in regs ---
    float plnew[10], prnew[10];
    if (v0 || v1){
        #pragma unroll
        for (int j=0;j<10;++j){
            int c = j*256 + t;
            if (FROMV){
                float sl = 0.f, sr = 0.f;
                for (int kz=0; kz<KS; ++kz){
                    sl += V[((size_t)(kz*2+0)*NB + b)*NN + c];
                    sr += V[((size_t)(kz*2+1)*NB + b)*NN + c];
                }
                plnew[j]=sl; prnew[j]=sr;
                PL[(size_t)node*NN + c] = sl;
                PR[(size_t)node*NN + c] = sr;
            } else {
                plnew[j] = PL[(size_t)node*NN + c];
                prnew[j] = PR[(size_t)node*NN + c];
            }
        }
    }

    // --- finish both refresh pairs: gates -> CH/CC + logit ---
    // e=0: (p, new) dst=p   : v = PL[p] + PRnew
    // e=1: (new, qn) dst=new: v = PLnew + PR[qn]
    for (int e=0; e<2; ++e){
        int4 rd = e ? r1 : r0;
        bool valid = e ? v1 : v0;
        float part = 0.f;
        if (valid){
            const float* OTH = e ? (PR + (size_t)(base+rd.z)*NN)
                                 : (PL + (size_t)(base+rd.y)*NN);
            const float* cl = Cc + (size_t)(base+rd.y)*HID;
            const float* cr = Cc + (size_t)(base+rd.z)*HID;
            int dst = rd.w;
            #pragma unroll
            for (int h2=0; h2<2; ++h2){
                int c = t + h2*256;
                float v[5];
                #pragma unroll
                for (int g=0; g<5; ++g){
                    int j = g*2 + h2;               // j*256+t == g*512+c
                    float mine = e ? plnew[j] : prnew[j];
                    v[g] = OTH[g*HID + c] + mine + bias[g*HID + c];
                }
                float cn = cl[c]*sigf(v[1]+1.f) + cr[c]*sigf(v[2]+1.f) + tanhf(v[3])*sigf(v[0]);
                float hn = sigf(v[4])*tanhf(cn);
                CH[(size_t)(base+dst)*HID + c] = hn;
                CC[(size_t)(base+dst)*HID + c] = cn;
                part += q[c]*hn;
            }
        }
        #pragma unroll
        for (int off=32; off; off>>=1) part += __shfl_xor(part, off);
        if ((t & 63) == 0) red[e*4 + (t>>6)] = part;
    }
    if (t < NSLOT) slg[t] = LG[base+t];
    __syncthreads();

    if (t == 0){
        float s0 = red[0]+red[1]+red[2]+red[3];
        float s1 = red[4]+red[5]+red[6]+red[7];
        if (v0){ LG[base+r0.w]=s0; slg[r0.w]=s0; }
        if (v1){ LG[base+r1.w]=s1; slg[r1.w]=s1; }
    }
    __syncthreads();

    int lb = len[b];
    if (i > lb-2){
        if (t==0){
            ROWS[b*2+0]=make_int4(0,0,0,-1);
            ROWS[b*2+1]=make_int4(0,0,0,-1);
            PROW[b]=base;
        }
        return;
    }

    // --- argmax (wave 0; first-max => smallest slot) ---
    if (t < 64){
        float val = (t < NSLOT)? slg[t] : -FLT_MAX;
        int idx = t;
        for (int off=1; off<64; off<<=1){
            float ov=__shfl_xor(val,off); int oi=__shfl_xor(idx,off);
            if (ov>val || (ov==val && oi<idx)){ val=ov; idx=oi; }
        }
        if (t==0) ss[0]=idx;
    }
    __syncthreads();
    int sstar = ss[0];

    // --- commit merged node ---
    {
        const float4* sh = (const float4*)(CH + (size_t)(base+sstar)*HID);
        const float4* sc = (const float4*)(CC + (size_t)(base+sstar)*HID);
        float4* dh = (float4*)(H  + (size_t)(base+sstar)*HID);
        float4* dc = (float4*)(Cc + (size_t)(base+sstar)*HID);
        if (t < 128) dh[t] = sh[t];
        else         dc[t-128] = sc[t-128];
    }
    // --- relink + emit next refresh pairs ---
    if (t == 0){
        int r  = NXT[base+sstar];
        int qn = NXT[base+r];
        int p  = PRV[base+sstar];
        NXT[base+sstar] = qn;
        if (qn >= 0) PRV[base+qn] = sstar;
        LG[base+r] = -FLT_MAX;
        if (qn < 0) LG[base+sstar] = -FLT_MAX;
        ROWS[b*2+0] = (p  >= 0) ? make_int4(b, p, sstar, p)      : make_int4(0,0,0,-1);
        ROWS[b*2+1] = (qn >= 0) ? make_int4(b, sstar, qn, sstar) : make_int4(0,0,0,-1);
        PROW[b] = base + sstar;
    }
}

// ---------------- step 0: argmax, commit, relink (phase-A logits) ----------------
__global__ void k_step0(const int* __restrict__ len,
                        float* __restrict__ H, float* __restrict__ Cc,
                        const float* __restrict__ CH, const float* __restrict__ CC,
                        float* __restrict__ LG, int* __restrict__ NXT,
                        int* __restrict__ PRV, int4* __restrict__ ROWS,
                        int* __restrict__ PROW)
{
    int b = blockIdx.x, lane = threadIdx.x;   // block = 64 = 1 wave
    int base = b*NSLOT;

    float val = (lane < NSLOT) ? LG[base+lane] : -FLT_MAX;
    int idx = lane;
    for (int off=1; off<64; off<<=1){
        float oval = __shfl_xor(val, off);
        int   oidx = __shfl_xor(idx, off);
        if (oval > val || (oval == val && oidx < idx)){ val = oval; idx = oidx; }
    }
    int sstar = idx;
    int r  = NXT[base+sstar];
    int qn = NXT[base+r];
    int p  = PRV[base+sstar];

    const float4* sh = (const float4*)(CH + (size_t)(base+sstar)*HID);
    const float4* sc = (const float4*)(CC + (size_t)(base+sstar)*HID);
    float4* dh = (float4*)(H  + (size_t)(base+sstar)*HID);
    float4* dc = (float4*)(Cc + (size_t)(base+sstar)*HID);
    dh[lane] = sh[lane]; dh[lane+64] = sh[lane+64];
    dc[lane] = sc[lane]; dc[lane+64] = sc[lane+64];

    if (lane==0){
        NXT[base+sstar] = qn;
        if (qn >= 0) PRV[base+qn] = sstar;
        LG[base+r] = -FLT_MAX;
        if (qn < 0) LG[base+sstar] = -FLT_MAX;
        ROWS[b*2+0] = (p  >= 0) ? make_int4(b, p, sstar, p)      : make_int4(0,0,0,-1);
        ROWS[b*2+1] = (qn >= 0) ? make_int4(b, sstar, qn, sstar) : make_int4(0,0,0,-1);
        PROW[b] = base + sstar;
    }
}

// ---------------- output: root = slot 0 ----------------
__global__ void k_out(const float* __restrict__ H, float* __restrict__ out)
{
    int b = blockIdx.x, t = threadIdx.x;       // 128 threads x float4
    ((float4*)out)[b*128 + t] = ((const float4*)(H + (size_t)b*NSLOT*HID))[t];
}

extern "C" void kernel_launch(void* const* d_in, const int* in_sizes, int n_in,
                              void* d_out, int out_size, void* d_ws, size_t ws_size,
                              hipStream_t stream)
{
    const float* in   = (const float*)d_in[0];
    const float* W    = (const float*)d_in[1];
    const float* bias = (const float*)d_in[2];
    const float* q    = (const float*)d_in[3];
    const int*   len  = (const int*)d_in[4];

    float* ws = (float*)d_ws;
    float* H  = ws + offH;
    float* Cc = ws + offC;
    float* CH = ws + offCH;
    float* CC = ws + offCC;
    float* LG = ws + offLG;
    int* NXT  = (int*)(ws + offNXT);
    int* PRV  = (int*)(ws + offPRV);
    int4* ROWS  = (int4*)(ws + offROWS);
    int4* ROWSA = (int4*)(ws + offROWSA);
    int*  ROWSN = (int*)(ws + offROWSN);
    int*  PROW  = (int*)(ws + offPROW);
    float* out = (float*)d_out;

    const size_t VSZ   = (size_t)2*2*NB*NN;             // KS=2 partials (5.2 MB)
    const size_t needV = (offBIG + VSZ + 2*(size_t)NNODE*NN) * sizeof(float);
    const bool useV = (ws_size >= needV);

    float* V  = ws + offBIG;
    float* PL = ws + offBIG + (useV ? VSZ : 0);
    float* PR = PL + (size_t)NNODE*NN;

    k_init <<<dim3(NNODE), dim3(256), 0, stream>>>(in, len, H, Cc, LG, NXT, PRV, ROWS);
    k_descA<<<dim3(NNODE/256), dim3(256), 0, stream>>>(len, ROWSA, ROWSN);

    // phase A: per-node products, pair-combine, first merge
    k_gemmP<8,32><<<dim3(NNODE/128, 2*NN/64), dim3(256), 0, stream>>>(ROWSN, H, W, PL, PR);
    k_combineP<<<dim3(AROWS), dim3(256), 0, stream>>>(ROWSA, PL, PR, Cc, bias, q, CH, CC, LG);
    k_step0<<<dim3(NB), dim3(64), 0, stream>>>(len, H, Cc, CH, CC, LG, NXT, PRV, ROWS, PROW);

    for (int i = 1; i < NL-1; ++i){
        if (useV){
            k_gemmPV<4,16><<<dim3(NB/64, 2*NN/64, 2), dim3(256), 0, stream>>>(PROW, H, W, V);
            k_combineStep<true><<<dim3(NB), dim3(256), 0, stream>>>(
                i, len, 2, V, PL, PR, ROWS, PROW, H, Cc, CH, CC, LG, NXT, PRV, bias, q);
        } else {
            k_gemmP<4,32><<<dim3(NB/64, 2*NN/64), dim3(256), 0, stream>>>(PROW, H, W, PL, PR);
            k_combineStep<false><<<dim3(NB), dim3(256), 0, stream>>>(
                i, len, 1, V, PL, PR, ROWS, PROW, H, Cc, CH, CC, LG, NXT, PRV, bias, q);
        }
    }
    k_out<<<dim3(NB), dim3(128), 0, stream>>>(H, out);
}